// Round 8
// baseline (185.569 us; speedup 1.0000x reference)
//
#include <hip/hip_runtime.h>
#include <stdint.h>
#include <stddef.h>

#define NROWS 8192
#define DIM   1024
#define RB    512      // fp4 bytes per row (DIM/2)
#define TEMP  10.0f

#define BM 128         // A panel rows per block
#define BN 128         // B cols per n-tile

typedef __attribute__((ext_vector_type(4))) int i32x4;
typedef __attribute__((ext_vector_type(8))) int i32x8;
typedef __attribute__((ext_vector_type(16))) float floatx16;

// async 16B global->LDS (global_load_lds_dwordx4); LDS dest is wave-uniform
// base + lane*16 -- all staging dests are slot*16 by construction.
__device__ __forceinline__ void load16_lds(const unsigned char* g, unsigned char* l) {
    __builtin_amdgcn_global_load_lds(
        (__attribute__((address_space(1))) void*)(g),
        (__attribute__((address_space(3))) void*)(l),
        16, 0, 0);
}

// fp4 e2m1 quantize of x (already in grid units, sigma~1): nearest of
// {0,.5,1,1.5,2,3,4,6} with sign. 7-threshold chain, branch-free.
__device__ __forceinline__ unsigned fp4q(float x) {
    float a = fabsf(x);
    a = fminf(a, 6.0f);
    unsigned c = (unsigned)(a >= 0.25f) + (unsigned)(a >= 0.75f)
               + (unsigned)(a >= 1.25f) + (unsigned)(a >= 1.75f)
               + (unsigned)(a >= 2.5f)  + (unsigned)(a >= 3.5f)
               + (unsigned)(a >= 5.0f);
    return c | ((__float_as_uint(x) >> 28) & 8u);
}

// fp4 operand: HW (cbsz=blgp=4) reads only regs 0..3; uppers UNDEF on purpose
// (no zero-movs, no pinned zero registers). Ran verified in r4/r7.
__device__ __forceinline__ i32x8 op8u(i32x4 lo) {
    return __builtin_shufflevector(lo, lo, 0, 1, 2, 3, -1, -1, -1, -1);
}

// ---------------------------------------------------------------------------
// Quantized layout (per matrix, 4 MB) -- MFMA-fragment-linear:
//   element e of row r: chunk c = e>>5 (16B = 32 fp4), it = c>>2,
//   ks = (c>>1)&1, fh = c&1
//   byte = it*524288 + (r>>5)*2048 + ks*1024 + fh*512 + (r&31)*16
// => per (rowgroup, it, ks): 1 KB fragment, lane-linear (lane = fh*32 + fr,
//    16 B per lane). Fragment reads need ZERO address swizzle; a 128-row
//    panel (4 rowgroups) within one it-slab is 8 KB CONTIGUOUS -> B slabs
//    stage as one contiguous 8 KB copy (1 load16_lds per thread).
// ---------------------------------------------------------------------------

// Wave-per-row L2 normalize + quantize to fp4 e2m1 at fixed scale 2^-5
// (values x32 -> sigma ~1 grid unit). Fragment-linear stores via small LDS
// transpose bounce. (Unchanged since r1; passes.)
__global__ __launch_bounds__(256) void normalize_kernel(
    const float* __restrict__ img, const float* __restrict__ txt,
    unsigned char* __restrict__ imgq, unsigned char* __restrict__ txtq,
    float* __restrict__ out)
{
    __shared__ __align__(16) unsigned short sc[4][256];   // [wave][c*64+lane]
    const int t = threadIdx.x;
    const int lane = t & 63, wave = t >> 6;
    const int gw = blockIdx.x * 4 + wave;                 // row id, 0..16383
    const float* src = (gw < NROWS) ? img + (size_t)gw * DIM
                                    : txt + (size_t)(gw - NROWS) * DIM;
    float4 v[4];
    float ss = 0.f;
#pragma unroll
    for (int c = 0; c < 4; c++) {
        v[c] = ((const float4*)src)[lane + 64 * c];
        ss += v[c].x * v[c].x + v[c].y * v[c].y + v[c].z * v[c].z + v[c].w * v[c].w;
    }
#pragma unroll
    for (int off = 32; off; off >>= 1) ss += __shfl_xor(ss, off);
    const float scale = 32.0f / fmaxf(sqrtf(ss), 1e-12f);   // x32 = fp4 grid
#pragma unroll
    for (int c = 0; c < 4; c++) {
        unsigned p = fp4q(v[c].x * scale)
                   | (fp4q(v[c].y * scale) << 4)
                   | (fp4q(v[c].z * scale) << 8)
                   | (fp4q(v[c].w * scale) << 12);
        sc[wave][c * 64 + lane] = (unsigned short)p;   // ushort u covers elems [4u,4u+4)
    }
    __syncthreads();
    // 128 store units: (rr = row in block 0..3, k = chunk 0..31). Chunk k =
    // ushorts [8k..8k+8) of row rr. 4 consecutive t share (it,ks,fh) and write
    // 4 consecutive fr*16 slots -> 64B-line coalesced.
    if (t < 128) {
        const int rr = t & 3, k = t >> 2;
        const int gr0 = blockIdx.x * 4;      // block never straddles img/txt (4 | 8192)
        unsigned char* dq = (gr0 < NROWS) ? imgq : txtq;
        const int r = (gr0 < NROWS ? gr0 : gr0 - NROWS) + rr;
        const int4 d = *(const int4*)&sc[rr][k * 8];
        const int it = k >> 2, ks = (k >> 1) & 1, fh = k & 1;
        *(int4*)(dq + (size_t)it * 524288 + (size_t)((r >> 5) * 2048
                 + ks * 1024 + fh * 512 + (r & 31) * 16)) = d;
    }
    if (gw == 0 && lane == 0) out[0] = 0.f;   // zero the atomic target
}

// NT-GEMM on fp4 e2m1 via MX-scaled MFMA 32x32x64.
// r7 post-mortem: B-from-global was bound by the per-CU vector-memory port
// (16 waves x 4 KB = 64 KB/CU per it-step through a ~64 B/cyc L1 port =
// 1024 cyc vs 566 cyc of MFMA). Fix: share B among waves via a
// double-buffered 8 KB LDS slab (one contiguous global_load_lds per thread
// per step) -> VMEM drops 4x to 16 KB/CU/step; operands now come from LDS.
// Sync = ONE __syncthreads per step: its implicit vmcnt(0) drains the single
// per-wave slab load issued a full MFMA region earlier (~free). LDS total =
// 64 KB A-panel + 16 KB B-dbuf = 81920 B EXACTLY -> 2 blocks/CU (163840 =
// 160 KB), and the two blocks run mutually out of phase, filling each
// other's barrier bubbles (what r1's 1-block/CU convoy lacked).
// Register plan (fits the (512,4) unified 128 cap, r4 lesson): acc[2]
// (32 AGPR) + a[2]/b[4] (24) + addr/scalars (~30) -> no spill (r7: VGPR=64).
__global__ __launch_bounds__(512, 4) void simloss_kernel(
    const unsigned char* __restrict__ An,   // img fp4, fragment-linear
    const unsigned char* __restrict__ Bn,   // txt fp4, fragment-linear
    const float* __restrict__ bias,
    float* __restrict__ out)
{
    __shared__ __align__(16) unsigned char As[8 * 8192];   // 64 KB A panel
    __shared__ __align__(16) unsigned char Bs[2][8192];    // 16 KB B dbuf

    const int t = threadIdx.x;
    const int lane = t & 63;
    const int wave = t >> 6;            // 0..7

    const int bid = blockIdx.x;         // 0..511
    const int blockM = bid >> 3;        // 0..63
    const int n0 = bid & 7;             // XCD-correlated N strip

    // ---- prologue: A panel (8 x 8 KB) + B slab 0; drained by the first
    //      __syncthreads inside the loop ----
    {
        const unsigned char* gA = An + (size_t)blockM * 8192 + t * 16;
#pragma unroll
        for (int it = 0; it < 8; it++)
            load16_lds(gA + (size_t)it * 524288, As + it * 8192 + t * 16);
        load16_lds(Bn + (size_t)n0 * 8192 + t * 16, &Bs[0][t * 16]);
    }

    // wave grid 4(M) x 2(N): rows = rgHalf*32, cols = nHalf*64 within tile
    const int rgHalf = wave >> 1;       // 0..3 (A rowgroup)
    const int nHalf = wave & 1;         // 0..1
    const int fr = lane & 31;
    const int fh = lane >> 5;
    const int vA0 = rgHalf * 2048 + lane * 16;   // A fragment base in LDS
    const int vB0 = nHalf * 4096 + lane * 16;    // B fragment base in slab

    const float bv = bias[0];
    const float c1 = -TEMP * 1.4426950408889634f / 1024.0f;  // on raw acc
    const float c0 = bv * 1.4426950408889634f;

    // diag: rows [blockM*128,+128) meet cols [n*128,+128) iff n == blockM,
    // i.e. (blockM&7)==n0 at j = blockM>>3 (then n = blockM exactly).
    const bool diagAny = (blockM & 7) == n0;
    const int jd = blockM >> 3;

    float accP = 0.f, accQ = 0.f, accD = 0.f;

    for (int j = 0; j < 8; ++j) {       // n-tile sweep: n = n0 + 8j
        floatx16 acc[2];
        acc[0] = (floatx16)(0.f);
        acc[1] = (floatx16)(0.f);

        for (int it = 0; it < 8; ++it) {
            const int s = j * 8 + it;   // global step 0..63
            // slab s is resident after this barrier (implicit vmcnt(0)
            // drains this wave's own slab-load issued one step ago; the
            // barrier makes every wave's share visible).
            __syncthreads();
            // issue slab s+1 into the other buffer; rides across the whole
            // step (WAR-safe: that buffer's readers drained pre-barrier).
            if (s < 63) {
                const int s1 = s + 1;
                const int n1 = n0 + 8 * (s1 >> 3);
                load16_lds(Bn + (size_t)(s1 & 7) * 524288 + (size_t)n1 * 8192
                               + t * 16,
                           &Bs[s1 & 1][t * 16]);
            }
            // fragment reads: A from resident panel, B from current slab
            i32x4 a[2], b[4];           // a[ks]; b[ni*2+ks]
#pragma unroll
            for (int ks = 0; ks < 2; ks++)
                a[ks] = *(const i32x4*)&As[vA0 + it * 8192 + ks * 1024];
#pragma unroll
            for (int q = 0; q < 4; q++)
                b[q] = *(const i32x4*)&Bs[s & 1][vB0 + (q >> 1) * 2048
                                               + (q & 1) * 1024];
#pragma unroll
            for (int ks = 0; ks < 2; ks++)
#pragma unroll
                for (int ni = 0; ni < 2; ni++)
                    acc[ni] = __builtin_amdgcn_mfma_scale_f32_32x32x64_f8f6f4(
                        op8u(a[ks]), op8u(b[ni * 2 + ks]), acc[ni],
                        4, 4,                 // cbsz=blgp=FP4(e2m1)
                        0, 0x7f7f7f7f,        // scale_a = 2^0
                        0, 0x7f7f7f7f);       // scale_b = 2^0
        }

        // ---- epilogue for this 32x64 wave tile. Raw acc = 1024*sim. ----
        // logit = -10*sim + b, x = label*logit;
        //   softplus(x) = (x+|x|)/2 + log(1+e^-|x|);
        //   sum(x)/2 = sum_diag(logit) - sum_all(logit)/2   (linear!)
        // log2 domain, PRODUCT trick: one v_log per 8 logits:
        //   sum log2(1+2^-|w|) = log2( prod (1+2^-|w_i|) ), prod in (1,256].
        // Runs between the barrier-less tail of step 8j+7 and the next
        // barrier -> overlaps the in-flight slab load and de-skews waves.
#pragma unroll
        for (int ni = 0; ni < 2; ni++) {
#pragma unroll
            for (int g = 0; g < 2; g++) {
                float prod = 1.0f;
#pragma unroll
                for (int r8 = 0; r8 < 8; r8++) {
                    float sv = acc[ni][g * 8 + r8];       // raw = 1024*sim
                    float w = fmaf(sv, c1, c0);
                    float aw = fabsf(w);
                    prod *= 1.0f + __builtin_amdgcn_exp2f(-aw);
                    accP = fmaf(0.5f, aw, accP);
                    accQ += sv;
                }
                accP += __builtin_amdgcn_logf(prod);      // v_log = log2
            }
        }
        if (diagAny && j == jd) {       // n == blockM here
            const int gi0 = blockM * BM + rgHalf * 32 + 4 * fh;
            const int gj0 = blockM * BN + nHalf * 64 + fr;
#pragma unroll
            for (int ni = 0; ni < 2; ni++)
#pragma unroll
                for (int reg = 0; reg < 16; reg++) {
                    int ig = gi0 + (reg & 3) + 8 * (reg >> 2);
                    int jg = gj0 + ni * 32;
                    if (ig == jg) accD += acc[ni][reg];
                }
        }
    }

    // ---- per-wave reduction + atomic (no LDS reduction: keeps LDS at
    //      exactly 80 KB for 2 blocks/CU; 4096 atomics total) ----
#pragma unroll
    for (int off = 32; off; off >>= 1) {
        accP += __shfl_xor(accP, off);
        accQ += __shfl_xor(accQ, off);
        accD += __shfl_xor(accD, off);
    }
    if (lane == 0) {
        // ln2*P + 5*(Qraw/1024) - 10*(Draw/1024); block consts via wave 0:
        // block covers 128x1024 elems -> -(Ne/2)*b = -65536*b; diag +128*b.
        float wcon = fmaf(0.6931471805599453f, accP,
                          fmaf(5.0f / 1024.0f, accQ,
                               (-TEMP / 1024.0f) * accD));
        if (wave == 0)
            wcon += fmaf(-65536.0f, bv, diagAny ? 128.0f * bv : 0.f);
        atomicAdd(out, wcon * (1.0f / 8192.0f));
    }
}

extern "C" void kernel_launch(void* const* d_in, const int* in_sizes, int n_in,
                              void* d_out, int out_size, void* d_ws, size_t ws_size,
                              hipStream_t stream) {
    const float* txt = (const float*)d_in[0];   // text_embeddings [8192][1024]
    const float* img = (const float*)d_in[1];   // image_embeddings [8192][1024]
    const float* bias = (const float*)d_in[2];  // [1]
    float* out = (float*)d_out;

    unsigned char* imgq = (unsigned char*)d_ws;                      // 4 MB fp4
    unsigned char* txtq = imgq + (size_t)NROWS * RB;                 // 4 MB fp4

    normalize_kernel<<<dim3(2 * NROWS / 4), dim3(256), 0, stream>>>(
        img, txt, imgq, txtq, out);

    simloss_kernel<<<dim3((NROWS / BM) * 8), dim3(512), 0, stream>>>(
        imgq, txtq, bias, out);
}